// Round 5
// baseline (70.971 us; speedup 1.0000x reference)
//
#include <hip/hip_runtime.h>
#include <hip/hip_bf16.h>

// GraphAttentionLayer: N=16, Cin=64, T=512, V=64. One block per b=n*T+t.
// One-barrier structure; wave w owns: mm1 rows 16w..16w+15 (X A-frags direct
// from global), softmax rows 16w..16w+15, mm2 output cols 16w..16w+15.
//   Y[c,v] = sum_u X[c,u]*W[u,v]            (MFMA, Wt prepped bf16 in ws)
//   p[i,j] = mask ? 2^(lrelu((f_i+g_j)*log2e)) : 0   (unnormalized)
//   out[c,v] = (sum_j Y[c,j]*p[v,j]) * rcp(S_v)      (S via ones-MFMA)

using bf16x8 = __attribute__((ext_vector_type(8))) short;
using f32x4  = __attribute__((ext_vector_type(4))) float;
typedef unsigned long long ull;

constexpr float ALPHA = 0.2f;
constexpr float LOG2E = 1.4426950408889634f;

__device__ __forceinline__ unsigned short f2bf(float f) {
    union { __hip_bfloat16 h; unsigned short s; } u;
    u.h = __float2bfloat16(f);
    return u.s;
}

// prep: Wt[v][u] = bf16(W[u][v]) into ws; maskbits[i] bit j = (Asum[i][j]>0)
__global__ void prep_kernel(const float* __restrict__ A,
                            const float* __restrict__ W,
                            unsigned short* __restrict__ Wt,
                            ull* __restrict__ mask) {
    const int tid = threadIdx.x;          // 256
    const int v = tid & 63, q = tid >> 6; // q=0..3
    #pragma unroll 4
    for (int m = 0; m < 16; ++m) {
        const int u = 16 * q + m;
        Wt[v * 64 + u] = f2bf(W[u * 64 + v]);
    }
    if (tid < 64) {
        ull m = 0;
        for (int j = 0; j < 64; ++j) {
            float s = A[tid * 64 + j] + A[4096 + tid * 64 + j] + A[8192 + tid * 64 + j];
            if (s > 0.f) m |= (1ull << j);
        }
        mask[tid] = m;
    }
}

__global__ __launch_bounds__(256, 7) void gat_kernel(
    const float* __restrict__ x,                 // (16,64,512,64) f32
    const float* __restrict__ a,                 // (128,)
    const unsigned short* __restrict__ Wt,       // (64,64) bf16, [v][u]
    const ull* __restrict__ maskbits,            // (64,)
    float* __restrict__ out)                     // (16,64,512,64) f32
{
    __shared__ unsigned short Yl[64 * 72];   // Y bf16, stride-72 rows
    __shared__ unsigned short Pl[64 * 72];   // P bf16, stride-72 rows
    __shared__ float fpart[4][64];
    __shared__ float gpart[4][64];
    __shared__ ull ml[64];

    const int tid = threadIdx.x;
    const int b = blockIdx.x;
    const int n = b >> 9, t = b & 511;
    const int w = tid >> 6, lane = tid & 63;
    const int fr = lane & 15, hi = lane >> 4;

    if (tid < 64) ml[tid] = maskbits[tid];

    // ---- X A-fragments straight from global (rows 16w+fr, 32B/lane) ----
    const float* xr = x + (size_t)n * 2097152 + (size_t)(16 * w + fr) * 32768
                        + (size_t)t * 64;
    bf16x8 af[2];
    #pragma unroll
    for (int kc = 0; kc < 2; ++kc) {
        float4 l0 = *(const float4*)(xr + 32 * kc + 8 * hi);
        float4 l1 = *(const float4*)(xr + 32 * kc + 8 * hi + 4);
        union { bf16x8 v; unsigned short s[8]; } u;
        u.s[0] = f2bf(l0.x); u.s[1] = f2bf(l0.y); u.s[2] = f2bf(l0.z); u.s[3] = f2bf(l0.w);
        u.s[4] = f2bf(l1.x); u.s[5] = f2bf(l1.y); u.s[6] = f2bf(l1.z); u.s[7] = f2bf(l1.w);
        af[kc] = u.v;
    }
    // ---- W B-fragments from prepped Wt (8KB, L2-hot) ----
    bf16x8 bw[4][2];
    #pragma unroll
    for (int cb = 0; cb < 4; ++cb)
        #pragma unroll
        for (int kc = 0; kc < 2; ++kc)
            bw[cb][kc] = *(const bf16x8*)&Wt[(16 * cb + fr) * 64 + 32 * kc + 8 * hi];

    // ---- mm1: Y rows 16w..16w+15, all col-blocks ----
    f32x4 acc[4] = {{0,0,0,0},{0,0,0,0},{0,0,0,0},{0,0,0,0}};
    #pragma unroll
    for (int kc = 0; kc < 2; ++kc)
        #pragma unroll
        for (int cb = 0; cb < 4; ++cb)
            acc[cb] = __builtin_amdgcn_mfma_f32_16x16x32_bf16(af[kc], bw[cb][kc], acc[cb], 0, 0, 0);

    // ---- epilogue: Y -> LDS (bf16); per-wave f/g partials (pre-scaled log2e) ----
    const float4 a1v = *(const float4*)&a[16 * w + 4 * hi];
    const float4 a2v = *(const float4*)&a[64 + 16 * w + 4 * hi];
    #pragma unroll
    for (int cb = 0; cb < 4; ++cb) {
        #pragma unroll
        for (int r = 0; r < 4; ++r)
            Yl[(16 * w + 4 * hi + r) * 72 + 16 * cb + fr] = f2bf(acc[cb][r]);
        float F = acc[cb][0]*a1v.x + acc[cb][1]*a1v.y + acc[cb][2]*a1v.z + acc[cb][3]*a1v.w;
        float G = acc[cb][0]*a2v.x + acc[cb][1]*a2v.y + acc[cb][2]*a2v.z + acc[cb][3]*a2v.w;
        F += __shfl_xor(F, 16, 64); F += __shfl_xor(F, 32, 64);
        G += __shfl_xor(G, 16, 64); G += __shfl_xor(G, 32, 64);
        if (lane < 16) {
            fpart[w][16 * cb + lane] = F * LOG2E;
            gpart[w][16 * cb + lane] = G * LOG2E;
        }
    }
    __syncthreads();   // the ONLY barrier: publishes Yl, fpart/gpart, ml

    // ---- softmax rows 16w..16w+15 (unnormalized, base-2) ----
    {
        const float gj = (gpart[0][lane] + gpart[1][lane]) + (gpart[2][lane] + gpart[3][lane]);
        #pragma unroll 4
        for (int k = 0; k < 16; ++k) {
            const int i = 16 * w + k;
            const ull mi = ml[i];
            const float fi = (fpart[0][i] + fpart[1][i]) + (fpart[2][i] + fpart[3][i]);
            const float s0 = fi + gj;
            const float e = fmaxf(s0, ALPHA * s0);   // lrelu (log2e>0 preserves it)
            const float p = (mi == 0ull) ? 1.0f
                          : (((mi >> lane) & 1ull) ? exp2f(e) : 0.0f);
            Pl[i * 72 + lane] = f2bf(p);
        }
    }
    // own-wave Pl write -> own-wave read: drain LDS queue, no block barrier
    asm volatile("s_waitcnt lgkmcnt(0)" ::: "memory");

    // ---- mm2: out cols 16w..16w+15 (B = own P rows), rows = all (Yl) ----
    bf16x8 pb0 = *(const bf16x8*)&Pl[(16 * w + fr) * 72 + 8 * hi];
    bf16x8 pb1 = *(const bf16x8*)&Pl[(16 * w + fr) * 72 + 32 + 8 * hi];
    union { bf16x8 v; unsigned short s[8]; } ones;
    #pragma unroll
    for (int j = 0; j < 8; ++j) ones.s[j] = 0x3f80;   // bf16 1.0
    f32x4 accS = {0, 0, 0, 0};
    accS = __builtin_amdgcn_mfma_f32_16x16x32_bf16(ones.v, pb0, accS, 0, 0, 0);
    accS = __builtin_amdgcn_mfma_f32_16x16x32_bf16(ones.v, pb1, accS, 0, 0, 0);

    f32x4 acc2[4] = {{0,0,0,0},{0,0,0,0},{0,0,0,0},{0,0,0,0}};
    #pragma unroll
    for (int rb = 0; rb < 4; ++rb) {
        bf16x8 y0 = *(const bf16x8*)&Yl[(16 * rb + fr) * 72 + 8 * hi];
        bf16x8 y1 = *(const bf16x8*)&Yl[(16 * rb + fr) * 72 + 32 + 8 * hi];
        acc2[rb] = __builtin_amdgcn_mfma_f32_16x16x32_bf16(y0, pb0, acc2[rb], 0, 0, 0);
        acc2[rb] = __builtin_amdgcn_mfma_f32_16x16x32_bf16(y1, pb1, acc2[rb], 0, 0, 0);
    }
    const float rs = __builtin_amdgcn_rcpf(accS[0]);   // S_v, v = 16w+fr
    float* op = out + (size_t)n * 2097152 + (size_t)t * 64 + 16 * w + fr;
    #pragma unroll
    for (int rb = 0; rb < 4; ++rb)
        #pragma unroll
        for (int r = 0; r < 4; ++r)
            op[(size_t)(16 * rb + 4 * hi + r) * 32768] = acc2[rb][r] * rs;
}

extern "C" void kernel_launch(void* const* d_in, const int* in_sizes, int n_in,
                              void* d_out, int out_size, void* d_ws, size_t ws_size,
                              hipStream_t stream) {
    const float* x = (const float*)d_in[0];
    const float* A = (const float*)d_in[1];
    const float* W = (const float*)d_in[2];
    const float* a = (const float*)d_in[3];
    float* out = (float*)d_out;
    unsigned short* Wt = (unsigned short*)d_ws;               // 8192 B
    ull* mask = (ull*)((char*)d_ws + 8192);                   // 512 B

    prep_kernel<<<1, 256, 0, stream>>>(A, W, Wt, mask);
    gat_kernel<<<16 * 512, 256, 0, stream>>>(x, a, Wt, mask, out);
}

// Round 7
// 63.533 us; speedup vs baseline: 1.1171x; 1.1171x over previous
//
#include <hip/hip_runtime.h>
#include <hip/hip_bf16.h>

// GraphAttentionLayer: N=16, Cin=64, T=512, V=64.
// TB=2: one block handles b=(n,t0) and (n,t0+1). Round-3 verified structure:
// stage(X2,Wt) -> bar -> mm1 x2 (+f/g partials from acc) -> bar ->
// softmax x2 (unnormalized, base-2) -> bar -> mm2 x2 (rowsum via ones-MFMA).
// Grid = 16*512/2 = 4096 blocks (r6 bug: had 2048, half of N unwritten).

using bf16x8 = __attribute__((ext_vector_type(8))) short;
using f32x4  = __attribute__((ext_vector_type(4))) float;
typedef unsigned long long ull;

constexpr float ALPHA = 0.2f;
constexpr float LOG2E = 1.4426950408889634f;

__device__ __forceinline__ unsigned short f2bf(float f) {
    union { __hip_bfloat16 h; unsigned short s; } u;
    u.h = __float2bfloat16(f);
    return u.s;
}

// prep: Wt[v][u] = bf16(W[u][v]); maskbits[i] bit j = (Asum[i][j]>0)
__global__ void prep_kernel(const float* __restrict__ A,
                            const float* __restrict__ W,
                            unsigned short* __restrict__ Wt,
                            ull* __restrict__ mask) {
    const int tid = threadIdx.x;          // 256
    const int v = tid & 63, q = tid >> 6; // q=0..3
    #pragma unroll 4
    for (int m = 0; m < 16; ++m) {
        const int u = 16 * q + m;
        Wt[v * 64 + u] = f2bf(W[u * 64 + v]);
    }
    if (tid < 64) {
        ull m = 0;
        for (int j = 0; j < 64; ++j) {
            float s = A[tid * 64 + j] + A[4096 + tid * 64 + j] + A[8192 + tid * 64 + j];
            if (s > 0.f) m |= (1ull << j);
        }
        mask[tid] = m;
    }
}

__global__ __launch_bounds__(256, 3) void gat_kernel(
    const float* __restrict__ x,                 // (16,64,512,64) f32
    const float* __restrict__ a,                 // (128,)
    const unsigned short* __restrict__ Wt,       // (64,64) bf16, [v][u]
    const ull* __restrict__ maskbits,            // (64,)
    float* __restrict__ out)                     // (16,64,512,64) f32
{
    // stride-72 ushort rows: b128 row-parallel access <=2-way on banks (free)
    __shared__ unsigned short Yb[2][64 * 72];  // X then Y, per tt
    __shared__ unsigned short Pb[2][64 * 72];  // Pb[0]: Wt then P(t0); Pb[1]: P(t1)
    __shared__ float fpart[2][4][64];
    __shared__ float gpart[2][4][64];
    __shared__ ull ml[64];

    const int tid = threadIdx.x;
    const int bb  = blockIdx.x;        // 0..4095
    const int n   = bb >> 8;           // 0..15 (256 blocks per n)
    const int t0  = (bb & 255) << 1;   // 0..510
    const int w   = tid >> 6, lane = tid & 63;
    const int fr  = lane & 15, hi = lane >> 4;

    if (tid < 64) ml[tid] = maskbits[tid];

    // ---- stage X for both t (coalesced float4, bf16 pack, b128 LDS writes) ----
    {
        const int c = tid >> 2, q = tid & 3;
        const float* xp = x + (size_t)n * 2097152 + (size_t)c * 32768
                            + (size_t)t0 * 64 + q * 16;
        #pragma unroll
        for (int tt = 0; tt < 2; ++tt) {
            float4 v0 = ((const float4*)(xp + 64 * tt))[0];
            float4 v1 = ((const float4*)(xp + 64 * tt))[1];
            float4 v2 = ((const float4*)(xp + 64 * tt))[2];
            float4 v3 = ((const float4*)(xp + 64 * tt))[3];
            union { bf16x8 v; unsigned short s[8]; } u0, u1;
            u0.s[0]=f2bf(v0.x); u0.s[1]=f2bf(v0.y); u0.s[2]=f2bf(v0.z); u0.s[3]=f2bf(v0.w);
            u0.s[4]=f2bf(v1.x); u0.s[5]=f2bf(v1.y); u0.s[6]=f2bf(v1.z); u0.s[7]=f2bf(v1.w);
            u1.s[0]=f2bf(v2.x); u1.s[1]=f2bf(v2.y); u1.s[2]=f2bf(v2.z); u1.s[3]=f2bf(v2.w);
            u1.s[4]=f2bf(v3.x); u1.s[5]=f2bf(v3.y); u1.s[6]=f2bf(v3.z); u1.s[7]=f2bf(v3.w);
            *(bf16x8*)&Yb[tt][c * 72 + q * 16]     = u0.v;
            *(bf16x8*)&Yb[tt][c * 72 + q * 16 + 8] = u1.v;
        }
    }
    // ---- stage Wt -> Pb[0] (2 x b128 copy per thread, fully coalesced) ----
    #pragma unroll
    for (int p = 0; p < 2; ++p) {
        const int r  = (tid >> 3) + 32 * p;
        const int cc = (tid & 7) * 8;
        *(bf16x8*)&Pb[0][r * 72 + cc] = *(const bf16x8*)&Wt[r * 64 + cc];
    }
    __syncthreads();

    // ---- W B-frags once, reused for both tt ----
    bf16x8 bw[4][2];
    #pragma unroll
    for (int cb = 0; cb < 4; ++cb)
        #pragma unroll
        for (int kc = 0; kc < 2; ++kc)
            bw[cb][kc] = *(const bf16x8*)&Pb[0][(16 * cb + fr) * 72 + 32 * kc + 8 * hi];

    const float4 a1v = *(const float4*)&a[16 * w + 4 * hi];
    const float4 a2v = *(const float4*)&a[64 + 16 * w + 4 * hi];

    // ---- mm1 x2: Y = X @ W; epilogue: Y->LDS bf16, f/g partials (log2e-scaled) ----
    #pragma unroll
    for (int tt = 0; tt < 2; ++tt) {
        bf16x8 af0 = *(const bf16x8*)&Yb[tt][(16 * w + fr) * 72 + 8 * hi];
        bf16x8 af1 = *(const bf16x8*)&Yb[tt][(16 * w + fr) * 72 + 32 + 8 * hi];
        f32x4 acc[4] = {{0,0,0,0},{0,0,0,0},{0,0,0,0},{0,0,0,0}};
        #pragma unroll
        for (int cb = 0; cb < 4; ++cb) {
            acc[cb] = __builtin_amdgcn_mfma_f32_16x16x32_bf16(af0, bw[cb][0], acc[cb], 0, 0, 0);
            acc[cb] = __builtin_amdgcn_mfma_f32_16x16x32_bf16(af1, bw[cb][1], acc[cb], 0, 0, 0);
        }
        #pragma unroll
        for (int cb = 0; cb < 4; ++cb) {
            #pragma unroll
            for (int r = 0; r < 4; ++r)
                Yb[tt][(16 * w + 4 * hi + r) * 72 + 16 * cb + fr] = f2bf(acc[cb][r]);
            float F = acc[cb][0]*a1v.x + acc[cb][1]*a1v.y + acc[cb][2]*a1v.z + acc[cb][3]*a1v.w;
            float G = acc[cb][0]*a2v.x + acc[cb][1]*a2v.y + acc[cb][2]*a2v.z + acc[cb][3]*a2v.w;
            F += __shfl_xor(F, 16, 64); F += __shfl_xor(F, 32, 64);
            G += __shfl_xor(G, 16, 64); G += __shfl_xor(G, 32, 64);
            if (lane < 16) {
                fpart[tt][w][16 * cb + lane] = F * LOG2E;
                gpart[tt][w][16 * cb + lane] = G * LOG2E;
            }
        }
    }
    __syncthreads();   // publishes Y, fpart/gpart; Wt (Pb[0]) now dead

    // ---- softmax x2: rows 16w..16w+15; f_i via register shfl, no per-row LDS ----
    #pragma unroll
    for (int tt = 0; tt < 2; ++tt) {
        const float gj = (gpart[tt][0][lane] + gpart[tt][1][lane])
                       + (gpart[tt][2][lane] + gpart[tt][3][lane]);
        const int myrow = 16 * w + fr;
        const float fvalL = (fpart[tt][0][myrow] + fpart[tt][1][myrow])
                          + (fpart[tt][2][myrow] + fpart[tt][3][myrow]);
        unsigned short* P = &Pb[tt][0];
        #pragma unroll 4
        for (int k = 0; k < 16; ++k) {
            const int i = 16 * w + k;
            const float fi = __shfl(fvalL, k, 64);   // lane k holds row 16w+k
            const ull mi = ml[i];
            const float s0 = fi + gj;
            const float e = fmaxf(s0, ALPHA * s0);   // lrelu (log2e>0 commutes)
            const float p = (mi == 0ull) ? 1.0f
                          : (((mi >> lane) & 1ull) ? exp2f(e) : 0.0f);
            P[i * 72 + lane] = f2bf(p);
        }
    }
    __syncthreads();

    // ---- mm2 x2: out[c,v] = (sum_j Y[c,j]P[v,j]) * rcp(S_v); S via ones-MFMA ----
    union { bf16x8 v; unsigned short s[8]; } ones;
    #pragma unroll
    for (int j = 0; j < 8; ++j) ones.s[j] = 0x3f80;   // bf16 1.0

    float* op = out + (size_t)n * 2097152 + (size_t)t0 * 64 + 16 * w + fr;
    #pragma unroll
    for (int tt = 0; tt < 2; ++tt) {
        const unsigned short* P = &Pb[tt][0];
        bf16x8 pb0 = *(const bf16x8*)&P[(16 * w + fr) * 72 + 8 * hi];
        bf16x8 pb1 = *(const bf16x8*)&P[(16 * w + fr) * 72 + 32 + 8 * hi];
        f32x4 accS = {0, 0, 0, 0};
        accS = __builtin_amdgcn_mfma_f32_16x16x32_bf16(ones.v, pb0, accS, 0, 0, 0);
        accS = __builtin_amdgcn_mfma_f32_16x16x32_bf16(ones.v, pb1, accS, 0, 0, 0);
        f32x4 acc2[4] = {{0,0,0,0},{0,0,0,0},{0,0,0,0},{0,0,0,0}};
        #pragma unroll
        for (int rb = 0; rb < 4; ++rb) {
            bf16x8 y0 = *(const bf16x8*)&Yb[tt][(16 * rb + fr) * 72 + 8 * hi];
            bf16x8 y1 = *(const bf16x8*)&Yb[tt][(16 * rb + fr) * 72 + 32 + 8 * hi];
            acc2[rb] = __builtin_amdgcn_mfma_f32_16x16x32_bf16(y0, pb0, acc2[rb], 0, 0, 0);
            acc2[rb] = __builtin_amdgcn_mfma_f32_16x16x32_bf16(y1, pb1, acc2[rb], 0, 0, 0);
        }
        const float rs = __builtin_amdgcn_rcpf(accS[0]);   // S_v, v = 16w+fr
        #pragma unroll
        for (int rb = 0; rb < 4; ++rb)
            #pragma unroll
            for (int r = 0; r < 4; ++r)
                op[(size_t)(16 * rb + 4 * hi + r) * 32768 + 64 * tt] = acc2[rb][r] * rs;
    }
}

extern "C" void kernel_launch(void* const* d_in, const int* in_sizes, int n_in,
                              void* d_out, int out_size, void* d_ws, size_t ws_size,
                              hipStream_t stream) {
    const float* x = (const float*)d_in[0];
    const float* A = (const float*)d_in[1];
    const float* W = (const float*)d_in[2];
    const float* a = (const float*)d_in[3];
    float* out = (float*)d_out;
    unsigned short* Wt = (unsigned short*)d_ws;     // 8192 B
    ull* mask = (ull*)((char*)d_ws + 8192);         // 512 B

    prep_kernel<<<1, 256, 0, stream>>>(A, W, Wt, mask);
    gat_kernel<<<4096, 256, 0, stream>>>(x, a, Wt, mask, out);
}

// Round 8
// 62.424 us; speedup vs baseline: 1.1369x; 1.0178x over previous
//
#include <hip/hip_runtime.h>
#include <hip/hip_bf16.h>

// GraphAttentionLayer: N=16, Cin=64, T=512, V=64. One block per b=n*T+t.
// r3-verified structure (54.6us), occupancy-tuned: LDS=20480B exactly ->
// 8 blocks/CU with __launch_bounds__(256,8).
// stage(X,Wt) -> bar -> mm1 (+f/g partials from acc) -> bar ->
// softmax (unnormalized, base-2, mask via s_load) -> bar ->
// mm2 (rowsum via ones-MFMA, fold rcp into epilogue).

using bf16x8 = __attribute__((ext_vector_type(8))) short;
using f32x4  = __attribute__((ext_vector_type(4))) float;
typedef unsigned long long ull;

constexpr float ALPHA = 0.2f;
constexpr float LOG2E = 1.4426950408889634f;

__device__ __forceinline__ unsigned short f2bf(float f) {
    union { __hip_bfloat16 h; unsigned short s; } u;
    u.h = __float2bfloat16(f);
    return u.s;
}

// prep: Wt[v][u] = bf16(W[u][v]); maskbits[i] bit j = (Asum[i][j]>0)
__global__ void prep_kernel(const float* __restrict__ A,
                            const float* __restrict__ W,
                            unsigned short* __restrict__ Wt,
                            ull* __restrict__ mask) {
    const int tid = threadIdx.x;          // 256
    const int v = tid & 63, q = tid >> 6; // q=0..3
    #pragma unroll 4
    for (int m = 0; m < 16; ++m) {
        const int u = 16 * q + m;
        Wt[v * 64 + u] = f2bf(W[u * 64 + v]);
    }
    if (tid < 64) {
        ull m = 0;
        for (int j = 0; j < 64; ++j) {
            float s = A[tid * 64 + j] + A[4096 + tid * 64 + j] + A[8192 + tid * 64 + j];
            if (s > 0.f) m |= (1ull << j);
        }
        mask[tid] = m;
    }
}

__global__ __launch_bounds__(256, 8) void gat_kernel(
    const float* __restrict__ x,                 // (16,64,512,64) f32
    const float* __restrict__ a,                 // (128,)
    const unsigned short* __restrict__ Wt,       // (64,64) bf16, [v][u]
    const ull* __restrict__ maskbits,            // (64,)
    float* __restrict__ out)                     // (16,64,512,64) f32
{
    // stride-72 ushort rows (144B): row-parallel b128 reads <=2-way on banks.
    // Total LDS = 9216 + 9216 + 1024 + 1024 = 20480 B = 160KB/8 exactly.
    __shared__ unsigned short XbYb[64 * 72];  // X (mm1 A) then Y (mm2 A)
    __shared__ unsigned short WtPb[64 * 72];  // Wt (mm1 B^T) then P (mm2 B^T)
    __shared__ float fpart[4][64];
    __shared__ float gpart[4][64];

    const int tid = threadIdx.x;
    const int b = blockIdx.x;
    const int n = b >> 9, t = b & 511;
    const int w = tid >> 6, lane = tid & 63;
    const int fr = lane & 15, hi = lane >> 4;
    const int fk = hi * 8;

    // ---- stage X (fp32 -> bf16), coalesced float4 reads, b128 LDS writes ----
    {
        const int c = tid >> 2, q = tid & 3;
        const float* xp = x + (size_t)n * 2097152 + (size_t)c * 32768
                            + (size_t)t * 64 + q * 16;
        float4 v0 = ((const float4*)xp)[0];
        float4 v1 = ((const float4*)xp)[1];
        float4 v2 = ((const float4*)xp)[2];
        float4 v3 = ((const float4*)xp)[3];
        union { bf16x8 v; unsigned short s[8]; } u0, u1;
        u0.s[0]=f2bf(v0.x); u0.s[1]=f2bf(v0.y); u0.s[2]=f2bf(v0.z); u0.s[3]=f2bf(v0.w);
        u0.s[4]=f2bf(v1.x); u0.s[5]=f2bf(v1.y); u0.s[6]=f2bf(v1.z); u0.s[7]=f2bf(v1.w);
        u1.s[0]=f2bf(v2.x); u1.s[1]=f2bf(v2.y); u1.s[2]=f2bf(v2.z); u1.s[3]=f2bf(v2.w);
        u1.s[4]=f2bf(v3.x); u1.s[5]=f2bf(v3.y); u1.s[6]=f2bf(v3.z); u1.s[7]=f2bf(v3.w);
        *(bf16x8*)&XbYb[c * 72 + q * 16]     = u0.v;
        *(bf16x8*)&XbYb[c * 72 + q * 16 + 8] = u1.v;
    }
    // ---- stage Wt (prepped bf16): 2 coalesced b128 copies per thread ----
    #pragma unroll
    for (int p = 0; p < 2; ++p) {
        const int r  = (tid >> 3) + 32 * p;
        const int cc = (tid & 7) * 8;
        *(bf16x8*)&WtPb[r * 72 + cc] = *(const bf16x8*)&Wt[r * 64 + cc];
    }
    __syncthreads();

    // ---- mm1: Y = X @ W; wave w owns rows 16w..16w+15 ----
    {
        f32x4 acc[4] = {{0,0,0,0},{0,0,0,0},{0,0,0,0},{0,0,0,0}};
        #pragma unroll
        for (int kc = 0; kc < 2; ++kc) {
            bf16x8 af = *(const bf16x8*)&XbYb[(16 * w + fr) * 72 + 32 * kc + fk];
            #pragma unroll
            for (int cb = 0; cb < 4; ++cb) {
                bf16x8 bfr = *(const bf16x8*)&WtPb[(16 * cb + fr) * 72 + 32 * kc + fk];
                acc[cb] = __builtin_amdgcn_mfma_f32_16x16x32_bf16(af, bfr, acc[cb], 0, 0, 0);
            }
        }
        // epilogue: Y -> LDS bf16 (own rows), f/g partials (log2e pre-scaled)
        const float4 a1v = *(const float4*)&a[16 * w + 4 * hi];
        const float4 a2v = *(const float4*)&a[64 + 16 * w + 4 * hi];
        #pragma unroll
        for (int cb = 0; cb < 4; ++cb) {
            #pragma unroll
            for (int r = 0; r < 4; ++r)
                XbYb[(16 * w + 4 * hi + r) * 72 + 16 * cb + fr] = f2bf(acc[cb][r]);
            float F = acc[cb][0]*a1v.x + acc[cb][1]*a1v.y + acc[cb][2]*a1v.z + acc[cb][3]*a1v.w;
            float G = acc[cb][0]*a2v.x + acc[cb][1]*a2v.y + acc[cb][2]*a2v.z + acc[cb][3]*a2v.w;
            F += __shfl_xor(F, 16, 64); F += __shfl_xor(F, 32, 64);
            G += __shfl_xor(G, 16, 64); G += __shfl_xor(G, 32, 64);
            if (lane < 16) {
                fpart[w][16 * cb + lane] = F * LOG2E;
                gpart[w][16 * cb + lane] = G * LOG2E;
            }
        }
    }
    __syncthreads();

    // ---- softmax rows 16w..16w+15 (unnormalized, base-2); mask via s_load ----
    {
        const float gj = (gpart[0][lane] + gpart[1][lane]) + (gpart[2][lane] + gpart[3][lane]);
        #pragma unroll 4
        for (int k = 0; k < 16; ++k) {
            const int i = 16 * w + k;
            const ull mi = maskbits[i];   // wave-uniform -> scalar load, L2-hot
            const float fi = (fpart[0][i] + fpart[1][i]) + (fpart[2][i] + fpart[3][i]);
            const float s0 = fi + gj;
            const float e = fmaxf(s0, ALPHA * s0);   // lrelu (log2e>0 commutes)
            const float p = (mi == 0ull) ? 1.0f
                          : (((mi >> lane) & 1ull) ? exp2f(e) : 0.0f);
            WtPb[i * 72 + lane] = f2bf(p);
        }
    }
    __syncthreads();

    // ---- mm2: out[c,v] = (sum_j Y[c,j]P[v,j]) * rcp(S_v); S via ones-MFMA ----
    {
        union { bf16x8 v; unsigned short s[8]; } ones;
        #pragma unroll
        for (int j = 0; j < 8; ++j) ones.s[j] = 0x3f80;   // bf16 1.0
        bf16x8 pb0 = *(const bf16x8*)&WtPb[(16 * w + fr) * 72 + fk];
        bf16x8 pb1 = *(const bf16x8*)&WtPb[(16 * w + fr) * 72 + 32 + fk];
        f32x4 accS = {0, 0, 0, 0};
        accS = __builtin_amdgcn_mfma_f32_16x16x32_bf16(ones.v, pb0, accS, 0, 0, 0);
        accS = __builtin_amdgcn_mfma_f32_16x16x32_bf16(ones.v, pb1, accS, 0, 0, 0);
        f32x4 acc2[4] = {{0,0,0,0},{0,0,0,0},{0,0,0,0},{0,0,0,0}};
        #pragma unroll
        for (int rb = 0; rb < 4; ++rb) {
            bf16x8 y0 = *(const bf16x8*)&XbYb[(16 * rb + fr) * 72 + fk];
            bf16x8 y1 = *(const bf16x8*)&XbYb[(16 * rb + fr) * 72 + 32 + fk];
            acc2[rb] = __builtin_amdgcn_mfma_f32_16x16x32_bf16(y0, pb0, acc2[rb], 0, 0, 0);
            acc2[rb] = __builtin_amdgcn_mfma_f32_16x16x32_bf16(y1, pb1, acc2[rb], 0, 0, 0);
        }
        const float rs = __builtin_amdgcn_rcpf(accS[0]);   // S_v, v = 16w+fr
        float* op = out + (size_t)n * 2097152 + (size_t)t * 64 + 16 * w + fr;
        #pragma unroll
        for (int rb = 0; rb < 4; ++rb)
            #pragma unroll
            for (int r = 0; r < 4; ++r)
                op[(size_t)(16 * rb + 4 * hi + r) * 32768] = acc2[rb][r] * rs;
    }
}

extern "C" void kernel_launch(void* const* d_in, const int* in_sizes, int n_in,
                              void* d_out, int out_size, void* d_ws, size_t ws_size,
                              hipStream_t stream) {
    const float* x = (const float*)d_in[0];
    const float* A = (const float*)d_in[1];
    const float* W = (const float*)d_in[2];
    const float* a = (const float*)d_in[3];
    float* out = (float*)d_out;
    unsigned short* Wt = (unsigned short*)d_ws;     // 8192 B
    ull* mask = (ull*)((char*)d_ws + 8192);         // 512 B

    prep_kernel<<<1, 256, 0, stream>>>(A, W, Wt, mask);
    gat_kernel<<<16 * 512, 256, 0, stream>>>(x, a, Wt, mask, out);
}